// Round 1
// baseline (48.124 us; speedup 1.0000x reference)
//
#include <hip/hip_runtime.h>

#define NB 16
#define NK 256
#define ND 256
#define NH 128
#define NM (NB * NK)  // 4096 rows

// ---------------------------------------------------------------------------
// Kernel 1:  A = x @ W1[:256]        (NM x NH)
//            C = x @ W1[256:] + b1   (NM x NH)
// grid (NM/64, 8): ntile 0..3 -> A cols, 4..7 -> C cols. block 256.
// BM=64, BN=32, BK=16, per-thread micro-tile 2x4.
// ---------------------------------------------------------------------------
__global__ __launch_bounds__(256) void k1_gemm(
    const float* __restrict__ x, const float* __restrict__ W1,
    const float* __restrict__ b1, float* __restrict__ A, float* __restrict__ C)
{
  __shared__ float Xs[16][64];  // [d][m] transposed
  __shared__ float Ws[16][32];  // [d][n]

  const int tid   = threadIdx.x;
  const int mtile = blockIdx.x;
  const int ntile = blockIdx.y;       // 0..7
  const bool isC  = ntile >= 4;
  const int wcol0 = (ntile & 3) * 32; // column base within the 128-col half
  const int wrow0 = isC ? 256 : 0;    // W1 row offset for the B-half
  const int m0    = mtile * 64;

  const int tx = tid & 7;   // 8 n-groups x 4 cols
  const int ty = tid >> 3;  // 32 m-groups x 2 rows

  const int xm = tid >> 2;        // 0..63
  const int xd = (tid & 3) * 4;   // 0,4,8,12
  const int wd = tid >> 3;        // 0..15 valid (tid<128)
  const int wn = (tid & 7) * 4;   // 0..28

  float acc[2][4] = {};

  for (int kk = 0; kk < ND; kk += 16) {
    float4 xv = *(const float4*)&x[(m0 + xm) * ND + kk + xd];
    float4 wv;
    if (tid < 128) wv = *(const float4*)&W1[(wrow0 + kk + wd) * NH + wcol0 + wn];
    __syncthreads();  // previous iteration's compute must finish
    Xs[xd + 0][xm] = xv.x;
    Xs[xd + 1][xm] = xv.y;
    Xs[xd + 2][xm] = xv.z;
    Xs[xd + 3][xm] = xv.w;
    if (tid < 128) *(float4*)&Ws[wd][wn] = wv;
    __syncthreads();
#pragma unroll
    for (int dk = 0; dk < 16; ++dk) {
      float2 av = *(const float2*)&Xs[dk][ty * 2];
      float4 bv = *(const float4*)&Ws[dk][tx * 4];
      acc[0][0] = fmaf(av.x, bv.x, acc[0][0]);
      acc[0][1] = fmaf(av.x, bv.y, acc[0][1]);
      acc[0][2] = fmaf(av.x, bv.z, acc[0][2]);
      acc[0][3] = fmaf(av.x, bv.w, acc[0][3]);
      acc[1][0] = fmaf(av.y, bv.x, acc[1][0]);
      acc[1][1] = fmaf(av.y, bv.y, acc[1][1]);
      acc[1][2] = fmaf(av.y, bv.z, acc[1][2]);
      acc[1][3] = fmaf(av.y, bv.w, acc[1][3]);
    }
  }

  const int c0 = wcol0 + tx * 4;  // 0..124 within the half
#pragma unroll
  for (int i = 0; i < 2; ++i) {
    const int r = m0 + ty * 2 + i;
    float4 v = make_float4(acc[i][0], acc[i][1], acc[i][2], acc[i][3]);
    if (isC) {
      v.x += b1[c0 + 0];
      v.y += b1[c0 + 1];
      v.z += b1[c0 + 2];
      v.w += b1[c0 + 3];
      *(float4*)&C[r * NH + c0] = v;
    } else {
      *(float4*)&A[r * NH + c0] = v;
    }
  }
}

// ---------------------------------------------------------------------------
// Kernel 2: fused pairwise-mean + GEMM2 + bias + residual.
//   mh[k1,h] = (K*a + sum_c + sum|a+c|) / (2K)    (exact relu-sum identity)
//   out[k1,d] = mh[k1,:] @ W2[:,d] + b2[d] + x[k1,d]
// grid (NB, NK/8), block 256. Group g=tid>>7 owns 4 k1-rows; h=tid&127.
// ---------------------------------------------------------------------------
__global__ __launch_bounds__(256) void k2_fused(
    const float* __restrict__ A, const float* __restrict__ C,
    const float* __restrict__ x, const float* __restrict__ W2,
    const float* __restrict__ b2, float* __restrict__ out)
{
  __shared__ float mh_s[NH][12];  // [h][r], stride 12 floats (48B, 16B-aligned)

  const int b      = blockIdx.x;
  const int k1t    = blockIdx.y;
  const int tid    = threadIdx.x;
  const int h      = tid & 127;
  const int g      = tid >> 7;  // 0,1
  const int k1base = k1t * 8;

  const float* Ap = A + (b * NK + k1base + g * 4) * NH + h;
  float av[4];
#pragma unroll
  for (int i = 0; i < 4; ++i) av[i] = Ap[i * NH];

  const float* Cp = C + b * NK * NH + h;
  float accAbs[4] = {0.f, 0.f, 0.f, 0.f};
  float accC = 0.f;
#pragma unroll 4
  for (int k2 = 0; k2 < NK; ++k2) {
    float c = Cp[k2 * NH];
    accC += c;
#pragma unroll
    for (int i = 0; i < 4; ++i) accAbs[i] += fabsf(av[i] + c);
  }

  float4 mh;
  mh.x = (256.f * av[0] + accC + accAbs[0]) * (1.f / 512.f);
  mh.y = (256.f * av[1] + accC + accAbs[1]) * (1.f / 512.f);
  mh.z = (256.f * av[2] + accC + accAbs[2]) * (1.f / 512.f);
  mh.w = (256.f * av[3] + accC + accAbs[3]) * (1.f / 512.f);
  *(float4*)&mh_s[h][g * 4] = mh;
  __syncthreads();

  // phase 2: thread = output column d
  const int d = tid;
  float acc2[8] = {};
#pragma unroll 4
  for (int hh = 0; hh < NH; ++hh) {
    float w2 = W2[hh * ND + d];
    float4 m0v = *(const float4*)&mh_s[hh][0];
    float4 m1v = *(const float4*)&mh_s[hh][4];
    acc2[0] = fmaf(m0v.x, w2, acc2[0]);
    acc2[1] = fmaf(m0v.y, w2, acc2[1]);
    acc2[2] = fmaf(m0v.z, w2, acc2[2]);
    acc2[3] = fmaf(m0v.w, w2, acc2[3]);
    acc2[4] = fmaf(m1v.x, w2, acc2[4]);
    acc2[5] = fmaf(m1v.y, w2, acc2[5]);
    acc2[6] = fmaf(m1v.z, w2, acc2[6]);
    acc2[7] = fmaf(m1v.w, w2, acc2[7]);
  }

  const float bias = b2[d];
  const float* xp = x + (b * NK + k1base) * ND + d;
  float* op = out + (b * NK + k1base) * ND + d;
#pragma unroll
  for (int r = 0; r < 8; ++r) op[r * ND] = acc2[r] + bias + xp[r * ND];
}

extern "C" void kernel_launch(void* const* d_in, const int* in_sizes, int n_in,
                              void* d_out, int out_size, void* d_ws, size_t ws_size,
                              hipStream_t stream) {
  const float* x  = (const float*)d_in[0];
  const float* W1 = (const float*)d_in[1];
  const float* b1 = (const float*)d_in[2];
  const float* W2 = (const float*)d_in[3];
  const float* b2 = (const float*)d_in[4];
  float* out = (float*)d_out;

  float* A = (float*)d_ws;          // NM*NH floats = 2 MB
  float* C = A + (size_t)NM * NH;   // NM*NH floats = 2 MB

  k1_gemm<<<dim3(NM / 64, 8), 256, 0, stream>>>(x, W1, b1, A, C);
  k2_fused<<<dim3(NB, NK / 8), 256, 0, stream>>>(A, C, x, W2, b2, out);
}

// Round 2
// 36.367 us; speedup vs baseline: 1.3233x; 1.3233x over previous
//
#include <hip/hip_runtime.h>

#define NB 16
#define NK 256
#define ND 256
#define NH 128
#define NM (NB * NK)  // 4096 rows

// ---------------------------------------------------------------------------
// Kernel 1:  A = x @ W1[:256]        (NM x NH)
//            C = x @ W1[256:] + b1   (NM x NH)
// grid (NM/64, 8): ntile 0..3 -> A cols, 4..7 -> C cols. block 256.
// BM=64, BN=32, BK=16, per-thread micro-tile 2x4.
// ---------------------------------------------------------------------------
__global__ __launch_bounds__(256) void k1_gemm(
    const float* __restrict__ x, const float* __restrict__ W1,
    const float* __restrict__ b1, float* __restrict__ A, float* __restrict__ C)
{
  __shared__ float Xs[16][64];  // [d][m] transposed
  __shared__ float Ws[16][32];  // [d][n]

  const int tid   = threadIdx.x;
  const int mtile = blockIdx.x;
  const int ntile = blockIdx.y;       // 0..7
  const bool isC  = ntile >= 4;
  const int wcol0 = (ntile & 3) * 32; // column base within the 128-col half
  const int wrow0 = isC ? 256 : 0;    // W1 row offset for the B-half
  const int m0    = mtile * 64;

  const int tx = tid & 7;   // 8 n-groups x 4 cols
  const int ty = tid >> 3;  // 32 m-groups x 2 rows

  const int xm = tid >> 2;        // 0..63
  const int xd = (tid & 3) * 4;   // 0,4,8,12
  const int wd = tid >> 3;        // 0..15 valid (tid<128)
  const int wn = (tid & 7) * 4;   // 0..28

  float acc[2][4] = {};

  for (int kk = 0; kk < ND; kk += 16) {
    float4 xv = *(const float4*)&x[(m0 + xm) * ND + kk + xd];
    float4 wv;
    if (tid < 128) wv = *(const float4*)&W1[(wrow0 + kk + wd) * NH + wcol0 + wn];
    __syncthreads();  // previous iteration's compute must finish
    Xs[xd + 0][xm] = xv.x;
    Xs[xd + 1][xm] = xv.y;
    Xs[xd + 2][xm] = xv.z;
    Xs[xd + 3][xm] = xv.w;
    if (tid < 128) *(float4*)&Ws[wd][wn] = wv;
    __syncthreads();
#pragma unroll
    for (int dk = 0; dk < 16; ++dk) {
      float2 av = *(const float2*)&Xs[dk][ty * 2];
      float4 bv = *(const float4*)&Ws[dk][tx * 4];
      acc[0][0] = fmaf(av.x, bv.x, acc[0][0]);
      acc[0][1] = fmaf(av.x, bv.y, acc[0][1]);
      acc[0][2] = fmaf(av.x, bv.z, acc[0][2]);
      acc[0][3] = fmaf(av.x, bv.w, acc[0][3]);
      acc[1][0] = fmaf(av.y, bv.x, acc[1][0]);
      acc[1][1] = fmaf(av.y, bv.y, acc[1][1]);
      acc[1][2] = fmaf(av.y, bv.z, acc[1][2]);
      acc[1][3] = fmaf(av.y, bv.w, acc[1][3]);
    }
  }

  const int c0 = wcol0 + tx * 4;  // 0..124 within the half
#pragma unroll
  for (int i = 0; i < 2; ++i) {
    const int r = m0 + ty * 2 + i;
    float4 v = make_float4(acc[i][0], acc[i][1], acc[i][2], acc[i][3]);
    if (isC) {
      v.x += b1[c0 + 0];
      v.y += b1[c0 + 1];
      v.z += b1[c0 + 2];
      v.w += b1[c0 + 3];
      *(float4*)&C[r * NH + c0] = v;
    } else {
      *(float4*)&A[r * NH + c0] = v;
    }
  }
}

// ---------------------------------------------------------------------------
// Kernel 2: fused pairwise-mean + GEMM2 + bias + residual.
//   mh[k1,h] = (K*a + sum_c + sum|a+c|) / (2K)    (exact relu-sum identity)
//   out[k1,d] = mh[k1,:] @ W2[:,d] + b2[d] + x[k1,d]
// v2: grid (NB, NK/4) = 1024 blocks (4 blocks/CU, 16 waves/CU), 256 threads.
// Each thread owns 2 k1-rows in phase 1 (R=2), unroll 16 for load ILP.
// ---------------------------------------------------------------------------
__global__ __launch_bounds__(256) void k2_fused(
    const float* __restrict__ A, const float* __restrict__ C,
    const float* __restrict__ x, const float* __restrict__ W2,
    const float* __restrict__ b2, float* __restrict__ out)
{
  __shared__ float mh_s[NH][4];  // [h][r] for the block's 4 k1-rows

  const int b      = blockIdx.x;
  const int k1t    = blockIdx.y;   // 0..63
  const int tid    = threadIdx.x;
  const int h      = tid & 127;
  const int g      = tid >> 7;     // 0,1
  const int k1base = k1t * 4;
  const int r0     = k1base + g * 2;

  const float* Ap = A + (b * NK + r0) * NH + h;
  const float av0 = Ap[0];
  const float av1 = Ap[NH];

  const float* Cp = C + b * NK * NH + h;
  float accC = 0.f, ab0 = 0.f, ab1 = 0.f;
#pragma unroll 16
  for (int k2 = 0; k2 < NK; ++k2) {
    float c = Cp[k2 * NH];
    accC += c;
    ab0 += fabsf(av0 + c);
    ab1 += fabsf(av1 + c);
  }

  mh_s[h][g * 2 + 0] = (256.f * av0 + accC + ab0) * (1.f / 512.f);
  mh_s[h][g * 2 + 1] = (256.f * av1 + accC + ab1) * (1.f / 512.f);
  __syncthreads();

  // phase 2: thread = output column d; 4 rows per thread.
  // mh_s reads are wave-uniform (broadcast, conflict-free).
  const int d = tid;
  float a0 = 0.f, a1 = 0.f, a2 = 0.f, a3 = 0.f;
#pragma unroll 8
  for (int hh = 0; hh < NH; ++hh) {
    float w = W2[hh * ND + d];
    float4 m = *(const float4*)&mh_s[hh][0];
    a0 = fmaf(m.x, w, a0);
    a1 = fmaf(m.y, w, a1);
    a2 = fmaf(m.z, w, a2);
    a3 = fmaf(m.w, w, a3);
  }

  const float bias = b2[d];
  const float* xp = x + (b * NK + k1base) * ND + d;
  float* op = out + (b * NK + k1base) * ND + d;
  op[0 * ND] = a0 + bias + xp[0 * ND];
  op[1 * ND] = a1 + bias + xp[1 * ND];
  op[2 * ND] = a2 + bias + xp[2 * ND];
  op[3 * ND] = a3 + bias + xp[3 * ND];
}

extern "C" void kernel_launch(void* const* d_in, const int* in_sizes, int n_in,
                              void* d_out, int out_size, void* d_ws, size_t ws_size,
                              hipStream_t stream) {
  const float* x  = (const float*)d_in[0];
  const float* W1 = (const float*)d_in[1];
  const float* b1 = (const float*)d_in[2];
  const float* W2 = (const float*)d_in[3];
  const float* b2 = (const float*)d_in[4];
  float* out = (float*)d_out;

  float* A = (float*)d_ws;          // NM*NH floats = 2 MB
  float* C = A + (size_t)NM * NH;   // NM*NH floats = 2 MB

  k1_gemm<<<dim3(NM / 64, 8), 256, 0, stream>>>(x, W1, b1, A, C);
  k2_fused<<<dim3(NB, NK / 4), 256, 0, stream>>>(A, C, x, W2, b2, out);
}